// Round 1
// baseline (344458.740 us; speedup 1.0000x reference)
//
#include <hip/hip_runtime.h>
#include <stdint.h>

// RNN-T greedy decode v3 — 3-round fence-free persistent pipeline.
//
// v2 (200 ms) spent ~35 of 40 µs/step in 4 device-wide sync rounds:
// agent fences (L2 writeback+invalidate per block per round), 448 blocks at
// 2/CU (role contention + stragglers), and a serial LDS argmax tree round.
//
// v3:
//  * 256 blocks total (1/CU guaranteed, ~50 KB LDS each):
//      128 gate blocks: 10 LSTM units x 16 rows; do gates -> h, then joint
//        pred (tanh) for their 10 j-cols, then speculative G = h@Wh (overlaps
//        the out round), then redundant per-row argmax over 64 candidates.
//      128 out blocks: 16 Wout cols x 16 rows (col-group 63 also owns blank).
//  * 3 rounds/step: F1 (h ready) -> F2 (tanh ready) -> F3 (candidates ready).
//  * NO cache fences: every mutable cross-block datum (h, tanh, candidates,
//    counters) moves via agent-scope relaxed atomic load/store (write-through
//    to MALL, coherent across XCDs). __syncthreads' vmcnt-drain orders data
//    stores before counter bumps. Immutable data (transposed weights, LUT,
//    encT) uses plain cached loads.
//  * h / tanh staged once per round into LDS (stride 644: conflict-free),
//    dots read LDS float4 + contiguous transposed-weight rows from L2.
//  * f64 accumulation kept (argmax semantics identical; smallest-index tie).

typedef unsigned int u32;
typedef unsigned long long u64;

constexpr int NGB = 128;          // gate+pred blocks
constexpr int NOB = 128;          // out blocks
constexpr int NBLK = NGB + NOB;   // 256 == #CUs

// ---- static device scratch ----
__device__ float g_encT[1000 * 32 * 640];  // enc@Wenc + b_joint, [T][B][J]
__device__ float g_lut[1025 * 2560];       // embed@Wx + b_lstm (row 1024 = b_lstm)
__device__ float g_WhT[2560 * 640];        // Wh^T   [4H][H]
__device__ float g_WpT[640 * 640];         // Wpred^T[J][H]
__device__ float g_WoT[1025 * 640];        // Wout^T [V+1][J]
__device__ float g_hnew[2 * 32 * 640];     // h_new, double-buffered by parity
__device__ float g_tnh[32 * 640];          // tanh(joint pre-act)
__device__ u64   g_cval[32 * 64];          // per-(row, col-group) best (f64 bits)
__device__ int   g_cidx[32 * 64];
__device__ u32   g_cnt[64 * 32];           // counters, 128 B apart

constexpr int F1L = 0,  F1R = 8;   // 8 leaves x 16 gate blocks
constexpr int F2L = 9,  F2R = 17;  // 8 leaves x 16 gate blocks
constexpr int F3L = 18, F3R = 26;  // 8 leaves x 16 out blocks

__device__ __forceinline__ float sigmf(float x) { return 1.0f / (1.0f + expf(-x)); }

// caller: thread 0, after __syncthreads() (all waves' atomic stores vmcnt-drained
// -> already visible at MALL; counters are MALL-coherent too, so no fence).
__device__ __forceinline__ void bump(int leaf, int root, int step) {
  u32 old = __hip_atomic_fetch_add(&g_cnt[leaf * 32], 1u, __ATOMIC_RELAXED, __HIP_MEMORY_SCOPE_AGENT);
  if (old + 1u == (u32)(step + 1) * 16u)
    __hip_atomic_fetch_add(&g_cnt[root * 32], 1u, __ATOMIC_RELAXED, __HIP_MEMORY_SCOPE_AGENT);
}

__device__ __forceinline__ void waitc(int root, u32 target) {
  if (threadIdx.x == 0) {
    while (__hip_atomic_load(&g_cnt[root * 32], __ATOMIC_RELAXED, __HIP_MEMORY_SCOPE_AGENT) < target)
      __builtin_amdgcn_s_sleep(1);
  }
  __syncthreads();  // codegen fence + exec barrier; data loads below are MALL-coherent atomics
}

// 320-length f64-accumulated dot: LDS h (float4) x global transposed weight row.
__device__ __forceinline__ double dot320(const float* __restrict__ h,
                                         const float* __restrict__ w) {
  double a0 = 0.0, a1 = 0.0;
#pragma unroll 8
  for (int k = 0; k < 320; k += 8) {
    float4 x0 = *(const float4*)(h + k);
    float4 w0 = *(const float4*)(w + k);
    float4 x1 = *(const float4*)(h + k + 4);
    float4 w1 = *(const float4*)(w + k + 4);
    a0 += (double)x0.x * w0.x; a0 += (double)x0.y * w0.y;
    a0 += (double)x0.z * w0.z; a0 += (double)x0.w * w0.w;
    a1 += (double)x1.x * w1.x; a1 += (double)x1.y * w1.y;
    a1 += (double)x1.z * w1.z; a1 += (double)x1.w * w1.w;
  }
  return a0 + a1;
}

// stage 16 rows x 640 f32 (coherent u64 atomic loads) -> LDS [16][644]
__device__ __forceinline__ void stage16(const float* gsrc, float* dst, int tid) {
  const u64* src = (const u64*)gsrc;
#pragma unroll 4
  for (int i = 0; i < 20; i++) {
    int idx = tid + i * 256;  // < 5120
    u64 v = __hip_atomic_load((u64*)(src + idx), __ATOMIC_RELAXED, __HIP_MEMORY_SCOPE_AGENT);
    int p2 = idx * 2;
    int bb = p2 / 640, kk = p2 - bb * 640;
    float2 f;
    f.x = __uint_as_float((u32)v);
    f.y = __uint_as_float((u32)(v >> 32));
    *(float2*)&dst[bb * 644 + kk] = f;
  }
}

// ---------------- precompute: LUT = embed @ Wx + b_lstm (row 1024 = b_lstm) ----------
__global__ __launch_bounds__(256) void k_lut(const float* __restrict__ embed,
                                             const float* __restrict__ Wx,
                                             const float* __restrict__ b_lstm) {
  const int tid = threadIdx.x;
  const int cg = blockIdx.x % 10, rg = blockIdx.x / 10;  // rg 0..128
  const int c = cg * 256 + tid;
  const int r0 = rg * 8;
  double acc[8];
  double bl = (double)b_lstm[c];
#pragma unroll
  for (int i = 0; i < 8; i++) acc[i] = bl;
  for (int e = 0; e < 640; e++) {
    double wx = (double)Wx[(size_t)e * 2560 + c];
#pragma unroll
    for (int i = 0; i < 8; i++) {
      int r = r0 + i;
      if (r < 1024) acc[i] += (double)embed[(size_t)r * 640 + e] * wx;
    }
  }
#pragma unroll
  for (int i = 0; i < 8; i++) {
    int r = r0 + i;
    if (r < 1025) g_lut[(size_t)r * 2560 + c] = (float)acc[i];
  }
  if (blockIdx.x == 0) {  // re-init counters every call (graph replay)
    for (int i = tid; i < 64 * 32; i += 256) g_cnt[i] = 0u;
  }
}

// ------------- precompute: encT[t][b][j] = sum_d enc[b][d][t]*Wenc[d][j] + b_joint[j] --
__global__ __launch_bounds__(256) void k_encproj(const float* __restrict__ enc,
                                                 const float* __restrict__ Wenc,
                                                 const float* __restrict__ bj) {
  __shared__ __align__(16) float As[16][68];
  __shared__ __align__(16) float Bs[16][68];
  const int tid = threadIdx.x;
  const int jt = blockIdx.x % 10, tt = blockIdx.x / 10;  // 10 j-tiles, 16 t-tiles
  const int b = blockIdx.y;
  const int t0 = tt * 64, j0 = jt * 64;
  const int ty = tid >> 4, tx = tid & 15;
  double acc[4][4] = {};
  const float* Ab = enc + (size_t)b * 640 * 1000;
  for (int d0 = 0; d0 < 640; d0 += 16) {
#pragma unroll
    for (int i = 0; i < 4; i++) {
      int idx = tid + i * 256;
      int d = idx >> 6, t = idx & 63;
      As[d][t] = (t0 + t < 1000) ? Ab[(size_t)(d0 + d) * 1000 + t0 + t] : 0.f;
      Bs[d][t] = Wenc[(size_t)(d0 + d) * 640 + j0 + t];
    }
    __syncthreads();
#pragma unroll
    for (int kk = 0; kk < 16; kk++) {
      float4 av = *(const float4*)&As[kk][ty * 4];
      float4 bv = *(const float4*)&Bs[kk][tx * 4];
      float a[4] = {av.x, av.y, av.z, av.w};
      float bb[4] = {bv.x, bv.y, bv.z, bv.w};
#pragma unroll
      for (int i = 0; i < 4; i++)
#pragma unroll
        for (int j = 0; j < 4; j++) acc[i][j] += (double)a[i] * (double)bb[j];
    }
    __syncthreads();
  }
#pragma unroll
  for (int i = 0; i < 4; i++) {
    int t = t0 + ty * 4 + i;
    if (t < 1000)
#pragma unroll
      for (int j = 0; j < 4; j++)
        g_encT[(size_t)t * 20480 + b * 640 + j0 + tx * 4 + j] =
            (float)(acc[i][j] + (double)bj[j0 + tx * 4 + j]);
  }
}

// ------------- precompute: transposed weights (contiguous rows for the dots) ----------
__global__ __launch_bounds__(256) void k_tr(const float* __restrict__ Wh,
                                            const float* __restrict__ Wpred,
                                            const float* __restrict__ Wout) {
  const int bid = blockIdx.x, tid = threadIdx.x;
  if (bid < 2560) {
    for (int k = tid; k < 640; k += 256) g_WhT[(size_t)bid * 640 + k] = Wh[(size_t)k * 2560 + bid];
  } else if (bid < 3200) {
    int c = bid - 2560;
    for (int k = tid; k < 640; k += 256) g_WpT[(size_t)c * 640 + k] = Wpred[(size_t)k * 640 + c];
  } else {
    int c = bid - 3200;  // < 1025
    for (int k = tid; k < 640; k += 256) g_WoT[(size_t)c * 640 + k] = Wout[(size_t)k * 1025 + c];
  }
}

// ------------------------------- persistent decode ------------------------------------
__global__ __launch_bounds__(256, 1) void k_decode(float* __restrict__ out,
                                                   const int* __restrict__ lens,
                                                   const float* __restrict__ b_out) {
  __shared__ __align__(16) float hst[16 * 644];   // staged h / tanh, 16 rows
  __shared__ __align__(16) double arena[1280];    // union: exA/ex2/exB/sval+sidx
  __shared__ int ssym[16];

  const int tid = threadIdx.x;
  const int bid = blockIdx.x;
  const int bloc = tid >> 4;        // local row 0..15
  const int c0 = tid & 15;

  if (bid < NGB) {
    // ================= GATE+PRED role: 10 units x 16 rows =================
    const int ug = bid >> 1, rg = bid & 1;
    const int u0 = ug * 10;
    const int b = rg * 16 + bloc;   // global batch row
    // slot0 gate pair-task t0 = c0 (20 tasks/row over 16 threads; slot1 if c0<4)
    const int ul0 = c0 % 10, pt0_ = c0 / 10;
    const int cA0 = (pt0_ ? 640 : 0) + u0 + ul0;     // i or f col
    const int cA1 = (pt0_ ? 1920 : 1280) + u0 + ul0; // g or o col
    const bool has2 = (c0 < 4);
    const int ulB = c0 + 6;                           // slot1: t1=c0+16, pt=1
    const int cB0 = 640 + u0 + ulB;
    const int cB1 = 1920 + u0 + ulB;
    const int len_r = lens[b];

    double G0 = 0.0, G1 = 0.0, G2 = 0.0, G3 = 0.0;  // committed h @ Wh (per col)
    double ccur = 0.0; float hcur = 0.0f;
    int last_r = 1024;
    int alive = (0 < len_r) ? 1 : 0;
    int ti = 0, si = 0;

    float* exA = (float*)arena;             // [16][20][2] f32
    double* ex2 = arena;                    // [16][10][2] f64
    double* exB = arena;                    // [16][40][2] f64
    double* sval = arena;                   // [256] f64
    int* sidx = (int*)(arena + 256);        // [256] i32

    for (int step = 0; step < 5000; step++) {
      // ---- phase A: gates = G + LUT[last]; pointwise -> h_new; publish ----
      float encf = 0.0f;
      if (c0 < 10) encf = g_encT[(size_t)ti * 20480 + b * 640 + u0 + c0];
      const float* lrow = g_lut + (size_t)last_r * 2560;
      exA[(bloc * 20 + c0) * 2 + 0] = (float)(G0 + (double)lrow[cA0]);
      exA[(bloc * 20 + c0) * 2 + 1] = (float)(G1 + (double)lrow[cA1]);
      if (has2) {
        exA[(bloc * 20 + c0 + 16) * 2 + 0] = (float)(G2 + (double)lrow[cB0]);
        exA[(bloc * 20 + c0 + 16) * 2 + 1] = (float)(G3 + (double)lrow[cB1]);
      }
      __syncthreads();
      double cn = 0.0; float hn = 0.0f;
      if (c0 < 10) {  // pt0 owners: have (i,g); partner t+10 has (f,o)
        float fi = exA[(bloc * 20 + c0) * 2 + 0];
        float fg = exA[(bloc * 20 + c0) * 2 + 1];
        float ff = exA[(bloc * 20 + c0 + 10) * 2 + 0];
        float fo = exA[(bloc * 20 + c0 + 10) * 2 + 1];
        cn = (double)sigmf(ff) * ccur + (double)sigmf(fi) * (double)tanhf(fg);
        hn = sigmf(fo) * tanhf((float)cn);
        __hip_atomic_store(&g_hnew[(step & 1) * 20480 + b * 640 + u0 + c0], hn,
                           __ATOMIC_RELAXED, __HIP_MEMORY_SCOPE_AGENT);
      }
      __syncthreads();  // vmcnt-drain: h stores at MALL before bump
      if (tid == 0) bump(F1L + (bid >> 4), F1R, step);
      waitc(F1R, (u32)(step + 1) * 8u);

      // ---- stage full h for our 16 rows into LDS ----
      stage16(g_hnew + (step & 1) * 20480 + rg * 10240, hst, tid);
      __syncthreads();

      // ---- pred: tanh(encT + h @ Wpred) for our 10 j-cols ----
      {
        double a = dot320(&hst[bloc * 644 + pt0_ * 320],
                          g_WpT + (size_t)(u0 + ul0) * 640 + pt0_ * 320);
        ex2[bloc * 20 + ul0 * 2 + pt0_] = a;
      }
      if (has2) {
        double a = dot320(&hst[bloc * 644 + 320],
                          g_WpT + (size_t)(u0 + ulB) * 640 + 320);
        ex2[bloc * 20 + ulB * 2 + 1] = a;
      }
      __syncthreads();
      if (c0 < 10) {
        double tot = ex2[bloc * 20 + c0 * 2 + 0] + ex2[bloc * 20 + c0 * 2 + 1];
        float th = tanhf((float)((double)encf + tot));
        __hip_atomic_store(&g_tnh[b * 640 + u0 + c0], th,
                           __ATOMIC_RELAXED, __HIP_MEMORY_SCOPE_AGENT);
      }
      __syncthreads();
      if (tid == 0) bump(F2L + (bid >> 4), F2R, step);

      // ---- phase B: speculative G_spec = h_new @ Wh (overlaps out round) ----
#pragma unroll
      for (int st = 0; st < 5; st++) {
        int stask = c0 + st * 16;           // 0..79
        int cs = stask % 40, ks = stask / 40;
        int t = cs >> 1, w = cs & 1;
        int ul = t % 10, pt = t / 10;
        int col = (w ? (pt ? 1920 : 1280) : (pt ? 640 : 0)) + u0 + ul;
        double a = dot320(&hst[bloc * 644 + ks * 320],
                          g_WhT + (size_t)col * 640 + ks * 320);
        exB[(bloc * 40 + cs) * 2 + ks] = a;
      }
      waitc(F3R, (u32)(step + 1) * 8u);

      // ---- commit: gather G_spec, redundant argmax over 64 candidates ----
      double nG0 = exB[(bloc * 40 + 2 * c0) * 2 + 0] + exB[(bloc * 40 + 2 * c0) * 2 + 1];
      double nG1 = exB[(bloc * 40 + 2 * c0 + 1) * 2 + 0] + exB[(bloc * 40 + 2 * c0 + 1) * 2 + 1];
      double nG2 = 0.0, nG3 = 0.0;
      if (has2) {
        nG2 = exB[(bloc * 40 + 2 * c0 + 32) * 2 + 0] + exB[(bloc * 40 + 2 * c0 + 32) * 2 + 1];
        nG3 = exB[(bloc * 40 + 2 * c0 + 33) * 2 + 0] + exB[(bloc * 40 + 2 * c0 + 33) * 2 + 1];
      }
      double bv = -1.0e300; int bi = 0x7fffffff;
#pragma unroll
      for (int q = 0; q < 4; q++) {
        int o = c0 + q * 16;
        u64 vb = __hip_atomic_load(&g_cval[b * 64 + o], __ATOMIC_RELAXED, __HIP_MEMORY_SCOPE_AGENT);
        int i2 = __hip_atomic_load(&g_cidx[b * 64 + o], __ATOMIC_RELAXED, __HIP_MEMORY_SCOPE_AGENT);
        double v = __longlong_as_double((long long)vb);
        if (v > bv || (v == bv && i2 < bi)) { bv = v; bi = i2; }
      }
      __syncthreads();  // exB reads done before arena reuse
      sval[tid] = bv; sidx[tid] = bi;
      __syncthreads();
      if (c0 == 0) {
        double v0 = sval[tid]; int i0 = sidx[tid];
        for (int q = 1; q < 16; q++) {
          double v = sval[tid + q]; int ii = sidx[tid + q];
          if (v > v0 || (v == v0 && ii < i0)) { v0 = v; i0 = ii; }
        }
        ssym[bloc] = i0;
      }
      __syncthreads();
      int sym = ssym[bloc];
      int em = (alive && sym != 1024) ? 1 : 0;
      if ((bid >> 1) == 0 && c0 == 0)
        out[(size_t)b * 5000 + step] = (float)(em ? sym : 1024);
      if (em) {
        last_r = sym;
        G0 = nG0; G1 = nG1;
        if (has2) { G2 = nG2; G3 = nG3; }
        if (c0 < 10) { ccur = cn; hcur = hn; }
      }
      alive = (si == 4) ? ((ti + 1 < len_r) ? 1 : 0) : em;
      si++; if (si == 5) { si = 0; ti++; }
    }
    if (c0 < 10) {  // cache_rnn_state = stack([h, c])
      out[160000 + b * 640 + u0 + c0] = hcur;
      out[160000 + 20480 + b * 640 + u0 + c0] = (float)ccur;
    }

  } else {
    // ================= OUT role: 16 Wout cols x 16 rows ====================
    const int o = bid - NGB;            // 0..127
    const int cg = o >> 1, rg = o & 1;
    const int b = rg * 16 + bloc;
    const int col = cg * 16 + c0;       // <= 1023
    const float* wrow = g_WoT + (size_t)col * 640;
    const double bo = (double)b_out[col];
    const bool blk = (cg == 63);        // also owns blank col 1024
    const double bo1024 = (double)b_out[1024];
    const float* wbl = g_WoT + (size_t)1024 * 640;

    for (int step = 0; step < 5000; step++) {
      waitc(F2R, (u32)(step + 1) * 8u);
      stage16(g_tnh + rg * 10240, hst, tid);
      __syncthreads();
      double a = bo + dot320(&hst[bloc * 644], wrow)
                    + dot320(&hst[bloc * 644 + 320], wrow + 320);
      double bv = a; int bi = col;
#pragma unroll
      for (int m = 1; m < 16; m <<= 1) {  // argmax over the 16 cols (16-lane group)
        double v2 = __shfl_xor(bv, m, 64);
        int i2 = __shfl_xor(bi, m, 64);
        if (v2 > bv || (v2 == bv && i2 < bi)) { bv = v2; bi = i2; }
      }
      if (blk) {  // blank logit: 16 lanes x 40 k, tree-sum
        const float* tb = &hst[bloc * 644 + c0 * 40];
        const float* wb2 = wbl + c0 * 40;
        double a2 = 0.0, a3 = 0.0;
#pragma unroll
        for (int k = 0; k < 40; k += 8) {
          float4 x0 = *(const float4*)(tb + k);
          float4 w0 = *(const float4*)(wb2 + k);
          float4 x1 = *(const float4*)(tb + k + 4);
          float4 w1 = *(const float4*)(wb2 + k + 4);
          a2 += (double)x0.x * w0.x; a2 += (double)x0.y * w0.y;
          a2 += (double)x0.z * w0.z; a2 += (double)x0.w * w0.w;
          a3 += (double)x1.x * w1.x; a3 += (double)x1.y * w1.y;
          a3 += (double)x1.z * w1.z; a3 += (double)x1.w * w1.w;
        }
        double ab = a2 + a3;
        ab += __shfl_xor(ab, 1, 64);
        ab += __shfl_xor(ab, 2, 64);
        ab += __shfl_xor(ab, 4, 64);
        ab += __shfl_xor(ab, 8, 64);
        if (c0 == 0) {
          double blv = ab + bo1024;
          if (blv > bv) { bv = blv; bi = 1024; }  // blank wins only on strict >
        }
      }
      if (c0 == 0) {
        __hip_atomic_store(&g_cval[b * 64 + cg], (u64)__double_as_longlong(bv),
                           __ATOMIC_RELAXED, __HIP_MEMORY_SCOPE_AGENT);
        __hip_atomic_store(&g_cidx[b * 64 + cg], bi,
                           __ATOMIC_RELAXED, __HIP_MEMORY_SCOPE_AGENT);
      }
      __syncthreads();  // vmcnt-drain before bump
      if (tid == 0) bump(F3L + (o >> 4), F3R, step);
    }
  }
}

extern "C" void kernel_launch(void* const* d_in, const int* in_sizes, int n_in,
                              void* d_out, int out_size, void* d_ws, size_t ws_size,
                              hipStream_t stream) {
  const float* enc = (const float*)d_in[0];
  const int* lens = (const int*)d_in[1];
  const float* embed = (const float*)d_in[2];
  const float* Wx = (const float*)d_in[3];
  const float* Wh = (const float*)d_in[4];
  const float* b_lstm = (const float*)d_in[5];
  const float* Wenc = (const float*)d_in[6];
  const float* Wpred = (const float*)d_in[7];
  const float* b_joint = (const float*)d_in[8];
  const float* Wout = (const float*)d_in[9];
  const float* b_out = (const float*)d_in[10];
  float* out = (float*)d_out;
  (void)d_ws; (void)ws_size; (void)in_sizes; (void)n_in; (void)out_size;

  hipLaunchKernelGGL(k_lut, dim3(1290), dim3(256), 0, stream, embed, Wx, b_lstm);
  hipLaunchKernelGGL(k_encproj, dim3(160, 32), dim3(256), 0, stream, enc, Wenc, b_joint);
  hipLaunchKernelGGL(k_tr, dim3(4225), dim3(256), 0, stream, Wh, Wpred, Wout);
  hipLaunchKernelGGL(k_decode, dim3(NBLK), dim3(256), 0, stream, out, lens, b_out);
}